// Round 7
// baseline (325.813 us; speedup 1.0000x reference)
//
#include <hip/hip_runtime.h>
#include <math.h>

#define D 64
#define CHUNK 128   // edges per wave in k_edge_agg
#define ROWP 68     // padded LDS row stride (halfs) for the pi round-trip

typedef __fp16 fp16x2 __attribute__((ext_vector_type(2)));
typedef _Float16 half8 __attribute__((ext_vector_type(8)));
typedef _Float16 half4v __attribute__((ext_vector_type(4)));
typedef __attribute__((ext_vector_type(4))) float f32x4;

union h8pun { half8 v; fp16x2 h2[4]; };

// ---------------------------------------------------------------------------
// Projection + folded prep.
//   roles (predicated on tid): start[] binary search; W2h permute+cast.
//   waves [0, wavesU):   u2e_h[r] = fp16(u2e[r])            (pure cvt-copy;
//                        q is no longer materialized -- computed on the fly
//                        in k_edge_agg from the gathered u2e_h row)
//   waves [wavesU, ..):  p~[r] = pi(u2e[nodes[r]] @ W1b + b1)  (MFMA)
__global__ __launch_bounds__(256) void k_proj_both(const float* __restrict__ u2e,
                                                   const int* __restrict__ nodes,
                                                   const float* __restrict__ W1,
                                                   const float* __restrict__ b1,
                                                   const float* __restrict__ W2,
                                                   _Float16* __restrict__ W2h,
                                                   const int* __restrict__ seg_ids,
                                                   int* __restrict__ start,
                                                   _Float16* __restrict__ u2e_h,
                                                   _Float16* __restrict__ p,
                                                   int U, int N, int E,
                                                   int wavesU, int wavesN) {
    // ---- folded prep roles ----
    int tid = blockIdx.x * blockDim.x + (int)threadIdx.x;
    if (tid <= N) {
        int lo = 0, hi = E;
        while (lo < hi) {
            int mid = (lo + hi) >> 1;
            if (seg_ids[mid] < tid) lo = mid + 1; else hi = mid;
        }
        start[tid] = lo;
    } else if (tid <= N + D * D) {
        int j = tid - (N + 1);
        int n = j >> 6, pos = j & 63;
        int k = (pos >> 2) + 16 * (pos & 3);   // pi_inv
        W2h[n * D + pos] = (_Float16)W2[k * D + n];
    }

    int lane = threadIdx.x & 63;
    int m = lane & 15, quad = lane >> 4;
    int wave = (blockIdx.x * blockDim.x + threadIdx.x) >> 6;

    if (wave < wavesU) {
        // ---- pure cvt-copy: u2e -> u2e_h ----
        int ngroups = (U + 15) / 16;
        for (int g = wave; g < ngroups; g += wavesU) {
            int r_ = g * 16 + m;
            if (r_ >= U) continue;
            const float4* arow = (const float4*)(u2e + (size_t)r_ * D);
            float4 x0 = arow[quad * 2], x1 = arow[quad * 2 + 1];
            float4 y0 = arow[8 + quad * 2], y1 = arow[8 + quad * 2 + 1];
            h8pun A0, A1;
            A0.h2[0] = __builtin_amdgcn_cvt_pkrtz(x0.x, x0.y);
            A0.h2[1] = __builtin_amdgcn_cvt_pkrtz(x0.z, x0.w);
            A0.h2[2] = __builtin_amdgcn_cvt_pkrtz(x1.x, x1.y);
            A0.h2[3] = __builtin_amdgcn_cvt_pkrtz(x1.z, x1.w);
            A1.h2[0] = __builtin_amdgcn_cvt_pkrtz(y0.x, y0.y);
            A1.h2[1] = __builtin_amdgcn_cvt_pkrtz(y0.z, y0.w);
            A1.h2[2] = __builtin_amdgcn_cvt_pkrtz(y1.x, y1.y);
            A1.h2[3] = __builtin_amdgcn_cvt_pkrtz(y1.z, y1.w);
            *(half8*)(u2e_h + (size_t)r_ * D + quad * 8) = A0.v;
            *(half8*)(u2e_h + (size_t)r_ * D + 32 + quad * 8) = A1.v;
        }
        return;
    }

    // ---- p-side MFMA projection (on-the-fly W1b transpose) ----
    int w0 = wave - wavesU;
    half8 Bf[2][4];
    float bv[4];
#pragma unroll
    for (int t = 0; t < 4; ++t) {
        int n = m + 16 * t;
        bv[t] = b1[n];
#pragma unroll
        for (int kh = 0; kh < 2; ++kh) {
            int k0 = D + kh * 32 + quad * 8;   // W1b rows
#pragma unroll
            for (int j = 0; j < 8; ++j) Bf[kh][t][j] = (_Float16)W1[(size_t)(k0 + j) * D + n];
        }
    }
    int ngroups = (N + 15) / 16;
    for (int g = w0; g < ngroups; g += wavesN) {
        int r_ = g * 16 + m;
        int rs = r_ < N ? r_ : N - 1;
        int src = nodes[rs];
        const float4* arow = (const float4*)(u2e + (size_t)src * D);
        float4 x0 = arow[quad * 2], x1 = arow[quad * 2 + 1];
        float4 y0 = arow[8 + quad * 2], y1 = arow[8 + quad * 2 + 1];
        h8pun A0, A1;
        A0.h2[0] = __builtin_amdgcn_cvt_pkrtz(x0.x, x0.y);
        A0.h2[1] = __builtin_amdgcn_cvt_pkrtz(x0.z, x0.w);
        A0.h2[2] = __builtin_amdgcn_cvt_pkrtz(x1.x, x1.y);
        A0.h2[3] = __builtin_amdgcn_cvt_pkrtz(x1.z, x1.w);
        A1.h2[0] = __builtin_amdgcn_cvt_pkrtz(y0.x, y0.y);
        A1.h2[1] = __builtin_amdgcn_cvt_pkrtz(y0.z, y0.w);
        A1.h2[2] = __builtin_amdgcn_cvt_pkrtz(y1.x, y1.y);
        A1.h2[3] = __builtin_amdgcn_cvt_pkrtz(y1.z, y1.w);
        f32x4 C[4];
#pragma unroll
        for (int t = 0; t < 4; ++t) C[t] = (f32x4){bv[t], bv[t], bv[t], bv[t]};
#pragma unroll
        for (int t = 0; t < 4; ++t) {
            C[t] = __builtin_amdgcn_mfma_f32_16x16x32_f16(A0.v, Bf[0][t], C[t], 0, 0, 0);
            C[t] = __builtin_amdgcn_mfma_f32_16x16x32_f16(A1.v, Bf[1][t], C[t], 0, 0, 0);
        }
        // pi-layout store: position m*4+t holds col m+16t
#pragma unroll
        for (int r = 0; r < 4; ++r) {
            int row = g * 16 + quad * 4 + r;
            if (row < N) {
                half4v hv = {(_Float16)C[0][r], (_Float16)C[1][r],
                             (_Float16)C[2][r], (_Float16)C[3][r]};
                *(half4v*)(p + (size_t)row * D + m * 4) = hv;
            }
        }
    }
}

// ---------------------------------------------------------------------------
// Merged edge+aggregation kernel.  One wave owns the nodes whose start lies
// in [w*CHUNK, (w+1)*CHUNK) -- node-aligned ranges, so every node is fully
// wave-local: NO atomics, NO stitch pass.  Per 16-edge set:
//   1. gather u2e_h[nbr] rows (the ONLY random gather in the whole pipeline)
//   2. q-proj on the fly: Cq = u @ W1a (MFMA; A-frag is the gathered row)
//   3. pi-store Cq to per-wave LDS, read back as A-frags (wave-internal,
//      lgkmcnt-ordered -- lgkmcnt is a per-wave counter)
//   4. x = relu(q + p[seg]); logits MFMA (W2h pi-compensated); ex = exp(l+b3)
//   5. segmented accumulate: acc += ex * u-row (still in registers!);
//      sorted segs -> flush per node boundary via m-butterfly + direct store
// Zero-neighbor fallback folded in as a predicated tid role.
__global__ __launch_bounds__(256) void k_edge_agg(const int* __restrict__ neigh_idx,
                                                  const int* __restrict__ seg_ids,
                                                  const _Float16* __restrict__ u2e_h,
                                                  const _Float16* __restrict__ p,
                                                  const _Float16* __restrict__ W2h,
                                                  const float* __restrict__ W1,
                                                  const float* __restrict__ b2,
                                                  const float* __restrict__ w3,
                                                  const float* __restrict__ b3,
                                                  const int* __restrict__ start,
                                                  const int* __restrict__ nodes,
                                                  const float* __restrict__ u2e,
                                                  float* __restrict__ out,
                                                  int E, int N, int nchunks) {
    __shared__ _Float16 lds_x[4][16 * ROWP];
    int wib = (int)threadIdx.x >> 6;
    _Float16* lx = lds_x[wib];

    int tid = blockIdx.x * blockDim.x + (int)threadIdx.x;
    // zero-neighbor fallback (degree-0 nodes never appear in seg_ids)
    if (tid < N) {
        if (start[tid + 1] == start[tid]) {
            const float4* src = (const float4*)(u2e + (size_t)nodes[tid] * D);
            float4* dst = (float4*)(out + (size_t)tid * D);
#pragma unroll
            for (int j = 0; j < 16; ++j) dst[j] = src[j];
        }
    }

    int lane = threadIdx.x & 63;
    int m = lane & 15, quad = lane >> 4;
    int wave = tid >> 6;
    if (wave >= nchunks) return;
    int e_lo = wave * CHUNK;

    // node-aligned edge range: nodes n with start[n] in [e_lo, e_lo+CHUNK)
    int lo = 0, hi = N + 1;
    while (lo < hi) { int mid = (lo + hi) >> 1; if (start[mid] < e_lo) lo = mid + 1; else hi = mid; }
    int s_begin = (lo <= N) ? start[lo] : E;
    int bound = e_lo + CHUNK;
    hi = N + 1;
    while (lo < hi) { int mid = (lo + hi) >> 1; if (start[mid] < bound) lo = mid + 1; else hi = mid; }
    int s_end = (lo <= N) ? start[lo] : E;
    if (s_begin >= s_end) return;

    // W1a fragments (on-the-fly transpose, L2-hot) + W2 fragments + biases
    half8 Bf1[2][4], Bf2[2][4];
    float b2v[4], w3v[4];
#pragma unroll
    for (int t = 0; t < 4; ++t) {
        int n = m + 16 * t;
        b2v[t] = b2[n];
        w3v[t] = w3[n];
        Bf2[0][t] = *(const half8*)(W2h + n * D + quad * 8);
        Bf2[1][t] = *(const half8*)(W2h + n * D + 32 + quad * 8);
#pragma unroll
        for (int kh = 0; kh < 2; ++kh) {
            int k0 = kh * 32 + quad * 8;
#pragma unroll
            for (int j = 0; j < 8; ++j) Bf1[kh][t][j] = (_Float16)W1[(size_t)(k0 + j) * D + n];
        }
    }
    float b3v = b3[0];
    const half8 hz = {0, 0, 0, 0, 0, 0, 0, 0};

    int cur_seg = seg_ids[s_begin];
    float acc0[8], acc1[8], dsum = 0.0f;
    bool dirty = false;
#pragma unroll
    for (int j = 0; j < 8; ++j) { acc0[j] = 0.0f; acc1[j] = 0.0f; }

    auto flush = [&]() {
#pragma unroll
        for (int off = 1; off <= 8; off <<= 1) {
#pragma unroll
            for (int j = 0; j < 8; ++j) {
                acc0[j] += __shfl_xor(acc0[j], off, 64);
                acc1[j] += __shfl_xor(acc1[j], off, 64);
            }
            dsum += __shfl_xor(dsum, off, 64);
        }
        if (m == 0) {
            float inv = 1.0f / dsum;
            float* o = out + (size_t)cur_seg * D + quad * 8;
            *(float4*)o = make_float4(acc0[0] * inv, acc0[1] * inv, acc0[2] * inv, acc0[3] * inv);
            *(float4*)(o + 4) = make_float4(acc0[4] * inv, acc0[5] * inv, acc0[6] * inv, acc0[7] * inv);
            float* o2 = o + 32;
            *(float4*)o2 = make_float4(acc1[0] * inv, acc1[1] * inv, acc1[2] * inv, acc1[3] * inv);
            *(float4*)(o2 + 4) = make_float4(acc1[4] * inv, acc1[5] * inv, acc1[6] * inv, acc1[7] * inv);
        }
#pragma unroll
        for (int j = 0; j < 8; ++j) { acc0[j] = 0.0f; acc1[j] = 0.0f; }
        dsum = 0.0f;
        dirty = false;
    };

    // prefetch first set's indices
    int ec0 = s_begin + m; if (ec0 > s_end - 1) ec0 = s_end - 1;
    int nb = neigh_idx[ec0], sg = seg_ids[ec0];

    for (int e0 = s_begin; e0 < s_end; e0 += 16) {
        int nb_c = nb, sg_c = sg;
        bool valid = (e0 + m) < s_end;
        // prefetch next set's indices (hide idx latency under this set)
        int e1 = e0 + 16;
        if (e1 < s_end) {
            int ec = e1 + m; if (ec > s_end - 1) ec = s_end - 1;
            nb = neigh_idx[ec]; sg = seg_ids[ec];
        }
        // the one random gather: u2e_h row (A-layout), kept for aggregation
        const half8* ur = (const half8*)(u2e_h + (size_t)nb_c * D);
        half8 ua0 = ur[quad], ua1 = ur[quad + 4];
        // p row (sorted seg -> L2-hot), pi layout
        const half8* pr = (const half8*)(p + (size_t)sg_c * D);
        half8 pa0 = pr[quad], pa1 = pr[quad + 4];
        // q-projection on the fly
        f32x4 Cq[4];
#pragma unroll
        for (int t = 0; t < 4; ++t) Cq[t] = (f32x4){0.0f, 0.0f, 0.0f, 0.0f};
#pragma unroll
        for (int t = 0; t < 4; ++t) {
            Cq[t] = __builtin_amdgcn_mfma_f32_16x16x32_f16(ua0, Bf1[0][t], Cq[t], 0, 0, 0);
            Cq[t] = __builtin_amdgcn_mfma_f32_16x16x32_f16(ua1, Bf1[1][t], Cq[t], 0, 0, 0);
        }
        // pi-store to LDS, read back as A-frags (C-layout -> A-layout)
#pragma unroll
        for (int r = 0; r < 4; ++r) {
            half4v hv = {(_Float16)Cq[0][r], (_Float16)Cq[1][r],
                         (_Float16)Cq[2][r], (_Float16)Cq[3][r]};
            *(half4v*)(lx + (quad * 4 + r) * ROWP + m * 4) = hv;
        }
        asm volatile("s_waitcnt lgkmcnt(0)" ::: "memory");  // wave-wide LDS drain
        half8 xq0 = *(const half8*)(lx + m * ROWP + quad * 8);
        half8 xq1 = *(const half8*)(lx + m * ROWP + 32 + quad * 8);
        half8 x0 = __builtin_elementwise_max(xq0 + pa0, hz);
        half8 x1 = __builtin_elementwise_max(xq1 + pa1, hz);
        // logits MFMA
        f32x4 Cl[4];
#pragma unroll
        for (int t = 0; t < 4; ++t) Cl[t] = (f32x4){b2v[t], b2v[t], b2v[t], b2v[t]};
#pragma unroll
        for (int t = 0; t < 4; ++t) {
            Cl[t] = __builtin_amdgcn_mfma_f32_16x16x32_f16(x0, Bf2[0][t], Cl[t], 0, 0, 0);
            Cl[t] = __builtin_amdgcn_mfma_f32_16x16x32_f16(x1, Bf2[1][t], Cl[t], 0, 0, 0);
        }
        float pl[4];
#pragma unroll
        for (int r = 0; r < 4; ++r) {
            float s = 0.0f;
#pragma unroll
            for (int t = 0; t < 4; ++t) s += fmaxf(Cl[t][r], 0.0f) * w3v[t];
            pl[r] = s;
        }
#pragma unroll
        for (int off = 1; off <= 8; off <<= 1) {
#pragma unroll
            for (int r = 0; r < 4; ++r) pl[r] += __shfl_xor(pl[r], off, 64);
        }
        // redistribute: lane (m,quad) needs ex of its OWN edge (e0+m)
        int srcl = (m >> 2) << 4;
        float t0 = __shfl(pl[0], srcl, 64), t1 = __shfl(pl[1], srcl, 64);
        float t2 = __shfl(pl[2], srcl, 64), t3 = __shfl(pl[3], srcl, 64);
        int rr = m & 3;
        float lg = rr == 0 ? t0 : rr == 1 ? t1 : rr == 2 ? t2 : t3;
        float exm = __expf(lg + b3v);
        // segmented accumulate (sorted segs; 1-2 walk iters typical)
        int sgw = valid ? sg_c : 0x7fffffff;
        bool active = valid;
        while (__any(active)) {
            int s0 = active ? sgw : 0x7fffffff;
#pragma unroll
            for (int off = 1; off <= 8; off <<= 1) s0 = min(s0, __shfl_xor(s0, off, 64));
            if (s0 != cur_seg) {
                if (dirty) flush();
                cur_seg = s0;
            }
            bool mine = active && (sgw == s0);
            float w = mine ? exm : 0.0f;
            dsum += w;
#pragma unroll
            for (int j = 0; j < 8; ++j) {
                acc0[j] += w * (float)ua0[j];
                acc1[j] += w * (float)ua1[j];
            }
            dirty = true;
            active = active && !mine;
        }
    }
    if (dirty) flush();
}

// ---------------------------------------------------------------------------
extern "C" void kernel_launch(void* const* d_in, const int* in_sizes, int n_in,
                              void* d_out, int out_size, void* d_ws, size_t ws_size,
                              hipStream_t stream) {
    const int* nodes = (const int*)d_in[0];
    const int* neigh_idx = (const int*)d_in[1];
    const int* seg_ids = (const int*)d_in[2];
    const float* u2e = (const float*)d_in[3];
    const float* W1 = (const float*)d_in[4];
    const float* b1 = (const float*)d_in[5];
    const float* W2 = (const float*)d_in[6];
    const float* b2 = (const float*)d_in[7];
    const float* w3 = (const float*)d_in[8];
    const float* b3 = (const float*)d_in[9];
    float* out = (float*)d_out;

    int N = in_sizes[0];
    int E = in_sizes[1];
    int U = in_sizes[3] / D;

    int nchunks = (E + CHUNK - 1) / CHUNK;

    char* ws = (char*)d_ws;
    size_t off = 0;
    auto alloc = [&](size_t bytes) {
        void* ptr = ws + off;
        off = (off + bytes + 255) & ~(size_t)255;
        return ptr;
    };
    int* start = (int*)alloc((size_t)(N + 1) * 4);
    _Float16* W2h = (_Float16*)alloc((size_t)D * D * 2);
    _Float16* p = (_Float16*)alloc((size_t)N * D * 2);
    _Float16* u2e_h = (_Float16*)alloc((size_t)U * D * 2);
    (void)ws_size;

    const int wavesU = 6144, wavesN = 2048;
    k_proj_both<<<(wavesU + wavesN) / 4, 256, 0, stream>>>(u2e, nodes, W1, b1, W2, W2h,
                                                           seg_ids, start, u2e_h, p,
                                                           U, N, E, wavesU, wavesN);
    k_edge_agg<<<(nchunks + 3) / 4, 256, 0, stream>>>(neigh_idx, seg_ids, u2e_h, p,
                                                      W2h, W1, b2, w3, b3, start,
                                                      nodes, u2e, out, E, N, nchunks);
}